// Round 4
// baseline (5089.522 us; speedup 1.0000x reference)
//
#include <hip/hip_runtime.h>
#include <hip/hip_bf16.h>

#define BATCH 1024
#define NLAYER 19
#define DTOT 267696

__device__ inline float ldf(const float* p){ return *p; }
__device__ inline float ldf(const __hip_bfloat16* p){ return __bfloat162float(*p); }

__device__ inline unsigned short f2bf(float x){
    __hip_bfloat16 h = __float2bfloat16(x);
    return *reinterpret_cast<unsigned short*>(&h);
}

// ---- dtype detector: flag=1 if inputs bf16, 0 if f32 ----
__global__ void detect_kernel(const unsigned short* __restrict__ xraw, int* __restrict__ flag)
{
    __shared__ int bad;
    if (threadIdx.x == 0) bad = 0;
    __syncthreads();
    int lbad = 0;
    for (int i = threadIdx.x; i < 4096; i += 256) {
        unsigned e = (xraw[i] >> 7) & 0xFF;
        if (e >= 147) lbad++;
    }
    if (lbad) atomicAdd(&bad, lbad);
    __syncthreads();
    if (threadIdx.x == 0) *flag = (bad == 0) ? 1 : 0;
}

__device__ inline bool flag_skip(const int* flag, int want)
{
    if (flag == nullptr) return false;
    return (*(volatile const int*)flag) != want;
}

// w_flat = origin + new_param @ P
template<typename T>
__global__ void wflat_kernel(const T* __restrict__ origin,
                             const T* __restrict__ P,
                             const T* __restrict__ npar,
                             float* __restrict__ wout, int D,
                             const int* flag, int want)
{
    if (flag_skip(flag, want)) return;
    int d = blockIdx.x*256 + threadIdx.x;
    if (d >= D) return;
    float acc = ldf(origin + d);
    #pragma unroll 8
    for (int k = 0; k < 40; k++)
        acc += ldf(npar + k) * ldf(P + (long long)k*D + d);
    wout[d] = acc;
}

__device__ inline void ldpair(const float* base, int p, float& x0, float& x1){
    const float2 v = ((const float2*)base)[p];
    x0 = v.x; x1 = v.y;
}
__device__ inline void ldpair(const __hip_bfloat16* base, int p, float& x0, float& x1){
    unsigned u = ((const unsigned int*)base)[p];
    x0 = __uint_as_float(u << 16);
    x1 = __uint_as_float(u & 0xffff0000u);
}

// ---- Tiled direct 3x3 conv, pad=1, one block per image. ----
// Input staged to LDS as bf16 (packed pairs) with zero column-border;
// optional fused BN+ReLU (of previous layer) applied during staging.
// Thread = (row r) x (col-half) x (co-group of TC). acc[TC][WT] in regs.
// Raw conv output (fp32) + per-co sum/sumsq stats (fp32 atomics).
template<typename T, int THREADS, int CIN, int COUT, int HIN, int WIN, int STRIDE,
         int ROWS, int HALVES, int COGS, int TC, int CH>
__global__ __launch_bounds__(THREADS) void conv_tile(
    const T* __restrict__ in, const float* __restrict__ wt,
    float* __restrict__ out, float* __restrict__ stats,
    const float* __restrict__ nstats, float ninvN,
    const int* flag, int want)
{
    if (flag_skip(flag, want)) return;
    constexpr int HOUT = HIN / STRIDE;
    constexpr int WOUT = WIN / STRIDE;
    constexpr int WT   = WOUT / HALVES;          // per-thread output cols
    constexpr int WP   = WIN + 6;                // padded row (shorts); odd uint stride
    constexpr int W2   = WP / 2;                 // row stride in uints
    constexpr int RVW  = (WT-1)*STRIDE + 3;      // input window width
    constexpr int NU   = (RVW + 2) / 2;          // uints to load per row window
    constexpr int RW   = (ROWS*HALVES > 64) ? 64 : ROWS*HALVES; // shuffle width
    static_assert(ROWS == HOUT, "rows");
    static_assert(ROWS*HALVES*COGS == THREADS, "threads");
    static_assert(COGS*TC == COUT, "cout");
    static_assert(CIN % CH == 0, "chunk");
    static_assert(WT % 4 == 0, "vec4 store");

    __shared__ unsigned int in_su[CIN*HIN*W2];
    __shared__ float w_s[COUT][CH][9];

    const int tid = threadIdx.x;
    const int b   = blockIdx.x;

    // ---- stage input image to LDS bf16, fused normalize+relu optional ----
    {
        const T* inb = in + (size_t)b*CIN*HIN*WIN;
        constexpr int NP = CIN*HIN*WIN/2;
        for (int p = tid; p < NP; p += THREADS) {
            int w2 = p % (WIN/2);
            int h  = (p / (WIN/2)) % HIN;
            int c  = p / ((WIN/2)*HIN);
            float x0, x1;
            ldpair(inb, p, x0, x1);
            if (nstats != nullptr) {
                float m = nstats[c]*ninvN;
                float v = fmaxf(nstats[64+c]*ninvN - m*m, 0.f);
                float rs = rsqrtf(v + 1e-5f);
                x0 = fmaxf((x0-m)*rs, 0.f);
                x1 = fmaxf((x1-m)*rs, 0.f);
            }
            unsigned int pk = (unsigned int)f2bf(x0) | ((unsigned int)f2bf(x1) << 16);
            in_su[(c*HIN + h)*W2 + 1 + w2] = pk;   // data at short-col 2+w
        }
        // zero column borders (short-col 1 = left pad, WIN+2 = right pad)
        unsigned short* in_ss = (unsigned short*)in_su;
        for (int i = tid; i < CIN*HIN; i += THREADS) {
            in_ss[i*WP + 1] = 0;
            in_ss[i*WP + WIN + 2] = 0;
        }
    }

    const int r    = tid % ROWS;
    const int hcv  = tid / ROWS;
    const int half = hcv % HALVES;
    const int cog  = hcv / HALVES;
    const int co0  = cog * TC;
    const int colbase = half * WT * STRIDE;      // even

    float acc[TC][WT];
    #pragma unroll
    for (int c = 0; c < TC; c++)
        #pragma unroll
        for (int t = 0; t < WT; t++) acc[c][t] = 0.f;

    for (int cc = 0; cc < CIN; cc += CH) {
        __syncthreads();   // staging done / previous chunk consumed
        for (int i = tid; i < COUT*CH*9; i += THREADS) {
            int k  = i % 9; int c2 = (i/9) % CH; int o = i/(9*CH);
            w_s[o][c2][k] = wt[((size_t)o*CIN + cc + c2)*9 + k];
        }
        __syncthreads();

        for (int ci = 0; ci < CH; ci++) {
            #pragma unroll
            for (int kh = 0; kh < 3; kh++) {
                const int ih = r*STRIDE + kh - 1;
                float rvf[RVW];
                if ((unsigned)ih < (unsigned)HIN) {
                    const unsigned int* up = in_su + ((cc+ci)*HIN + ih)*W2 + (colbase >> 1);
                    unsigned int U[NU];
                    #pragma unroll
                    for (int k = 0; k < NU; k++) U[k] = up[k];
                    // rv[j] = input col (colbase + j - 1); phys short 1+colbase+j
                    #pragma unroll
                    for (int j = 0; j < RVW; j++)
                        rvf[j] = (j & 1) ? __uint_as_float(U[(j+1) >> 1] << 16)
                                         : __uint_as_float(U[j >> 1] & 0xffff0000u);
                } else {
                    #pragma unroll
                    for (int j = 0; j < RVW; j++) rvf[j] = 0.f;
                }
                float wv[TC][3];
                #pragma unroll
                for (int c = 0; c < TC; c++)
                    #pragma unroll
                    for (int kw = 0; kw < 3; kw++)
                        wv[c][kw] = w_s[co0+c][ci][kh*3+kw];
                #pragma unroll
                for (int c = 0; c < TC; c++)
                    #pragma unroll
                    for (int kw = 0; kw < 3; kw++)
                        #pragma unroll
                        for (int t = 0; t < WT; t++)
                            acc[c][t] += rvf[t*STRIDE + kw] * wv[c][kw];
            }
        }
    }

    // ---- epilogue: fp32 store (float4) + per-co stats ----
    #pragma unroll
    for (int c = 0; c < TC; c++) {
        float* ob = out + (((size_t)b*COUT + co0 + c)*HOUT + r)*WOUT + half*WT;
        #pragma unroll
        for (int t = 0; t < WT; t += 4)
            *(float4*)(ob + t) = make_float4(acc[c][t], acc[c][t+1], acc[c][t+2], acc[c][t+3]);
        float ss = 0.f, qq = 0.f;
        #pragma unroll
        for (int t = 0; t < WT; t++) { ss += acc[c][t]; qq += acc[c][t]*acc[c][t]; }
        #pragma unroll
        for (int off = RW/2; off > 0; off >>= 1) {
            ss += __shfl_down(ss, off, RW);
            qq += __shfl_down(qq, off, RW);
        }
        if ((tid & (RW-1)) == 0) {
            atomicAdd(&stats[co0+c],    ss);
            atomicAdd(&stats[64+co0+c], qq);
        }
    }
}

// y = relu((x-mean)*rsqrt(var+eps)), in-place (used for layer 0 only)
__global__ void bn_relu_kernel(float* __restrict__ x, const float* __restrict__ stats,
    int C, int HW, float invN, int n)
{
    int i = blockIdx.x*256 + threadIdx.x;
    if (i >= n) return;
    int c = (i / HW) % C;
    float m = stats[c] * invN;
    float v = fmaxf(stats[64+c] * invN - m*m, 0.f);
    x[i] = fmaxf((x[i]-m)*rsqrtf(v + 1e-5f), 0.f);
}

// y = relu(bn(x) + shortcut(prev)), in-place over x
__global__ void bn_add_relu_kernel(float* __restrict__ x, const float* __restrict__ prev,
    const float* __restrict__ stats, int C, int H, int W, int prevC, int padF, int stride,
    float invN, int n)
{
    int i = blockIdx.x*256 + threadIdx.x;
    if (i >= n) return;
    int wq = i % W;
    int hq = (i / W) % H;
    int c  = (i / (W*H)) % C;
    int b  = i / (W*H*C);
    float m = stats[c]*invN;
    float v = fmaxf(stats[64+c]*invN - m*m, 0.f);
    float val = (x[i]-m)*rsqrtf(v + 1e-5f);
    float sc = 0.f;
    if (stride == 1) {
        sc = prev[i];
    } else {
        int pc = c - padF;
        if (pc >= 0 && pc < prevC)
            sc = prev[(((long long)b*prevC + pc)*(H*2) + 2*hq)*(W*2) + 2*wq];
    }
    x[i] = fmaxf(val + sc, 0.f);
}

__device__ inline void stf(float* p, float v){ *p = v; }
__device__ inline void stf(__hip_bfloat16* p, float v){ *p = __float2bfloat16(v); }

// mean over 8x8 spatial -> (B,64); out = feat @ Wfc^T + bfc -> (B,10)
template<typename T>
__global__ void poolfc_kernel(const float* __restrict__ in,
    const T* __restrict__ Wfc, const T* __restrict__ bfc,
    T* __restrict__ out, const int* flag, int want)
{
    if (flag_skip(flag, want)) return;
    int b = blockIdx.x;
    int c = threadIdx.x; // 64 threads
    const float* p = in + ((long long)b*64 + c)*64;
    float s = 0.f;
    #pragma unroll
    for (int i = 0; i < 64; i++) s += p[i];
    __shared__ float feat[64];
    feat[c] = s * (1.f/64.f);
    __syncthreads();
    if (c < 10) {
        float o = ldf(bfc + c);
        for (int k = 0; k < 64; k++)
            o += feat[k] * ldf(Wfc + c*64 + k);
        stf(out + b*10 + c, o);
    }
}

extern "C" void kernel_launch(void* const* d_in, const int* in_sizes, int n_in,
                              void* d_out, int out_size, void* d_ws, size_t ws_size,
                              hipStream_t stream)
{
    char* ws = (char*)d_ws;
    float* wflat = (float*)(ws);                  // DTOT floats
    float* stats = (float*)(ws + 1114112);        // 19 slots x 256 floats
    int*   flag  = (int*)  (ws + 1114112 + 32768);
    float* bufA  = (float*)(ws + 1179648);
    float* bufB  = (float*)(ws + 1179648 + 67108864);
    float* bufC  = (float*)(ws + 1179648 + 2*67108864ULL);

    hipMemsetAsync(stats, 0, 32768, stream);
    detect_kernel<<<1, 256, 0, stream>>>((const unsigned short*)d_in[0], flag);

    wflat_kernel<__hip_bfloat16><<<(DTOT+255)/256, 256, 0, stream>>>(
        (const __hip_bfloat16*)d_in[1], (const __hip_bfloat16*)d_in[2],
        (const __hip_bfloat16*)d_in[3], wflat, DTOT, flag, 1);
    wflat_kernel<float><<<(DTOT+255)/256, 256, 0, stream>>>(
        (const float*)d_in[1], (const float*)d_in[2],
        (const float*)d_in[3], wflat, DTOT, flag, 0);

    static const int WOFF[NLAYER] = {0,432,2736,5040,7344,9648,11952,14256,18864,
        28080,37296,46512,55728,64944,83376,120240,157104,193968,230832};
    const float iN32 = 1.f/1048576.f;   // B*32*32
    const float iN16 = 1.f/262144.f;    // B*16*16
    const float iN8  = 1.f/65536.f;     // B*8*8

    // ---- layer 0 (input dtype-guarded both ways) ----
    conv_tile<__hip_bfloat16,512, 3,16,32,32,1, 32,4,4,4, 3><<<BATCH,512,0,stream>>>(
        (const __hip_bfloat16*)d_in[0], wflat+WOFF[0], bufA, stats, nullptr, 0.f, flag, 1);
    conv_tile<float,512, 3,16,32,32,1, 32,4,4,4, 3><<<BATCH,512,0,stream>>>(
        (const float*)d_in[0], wflat+WOFF[0], bufA, stats, nullptr, 0.f, flag, 0);
    bn_relu_kernel<<<65536,256,0,stream>>>(bufA, stats, 16, 1024, iN32, 16777216);

    float* cur = bufA;
    float* f1  = bufB;
    float* f2  = bufC;

    #define CONV16(l, src, dst, nst, niv) \
        conv_tile<float,512, 16,16,32,32,1, 32,4,4,4, 16><<<BATCH,512,0,stream>>>( \
            src, wflat+WOFF[l], dst, stats+(l)*256, nst, niv, nullptr, 0)
    #define CONV32(l, src, dst, nst, niv) \
        conv_tile<float,256, 32,32,16,16,1, 16,2,8,4, 16><<<BATCH,256,0,stream>>>( \
            src, wflat+WOFF[l], dst, stats+(l)*256, nst, niv, nullptr, 0)
    #define CONV64(l, src, dst, nst, niv) \
        conv_tile<float,256, 64,64,8,8,1, 8,1,32,2, 16><<<BATCH,256,0,stream>>>( \
            src, wflat+WOFF[l], dst, stats+(l)*256, nst, niv, nullptr, 0)

    // blocks 0-2: 16ch 32x32
    for (int bi = 0; bi < 3; bi++) {
        int la = 1 + bi*2, lb = 2 + bi*2;
        CONV16(la, cur, f1, nullptr, 0.f);
        CONV16(lb, f1, f2, stats+la*256, iN32);
        bn_add_relu_kernel<<<65536,256,0,stream>>>(
            f2, cur, stats+lb*256, 16, 32, 32, 16, 0, 1, iN32, 16777216);
        float* t = f2; f2 = cur; cur = t;
    }
    // block 3: stride2 16->32ch
    conv_tile<float,256, 16,32,32,32,2, 16,2,8,4, 16><<<BATCH,256,0,stream>>>(
        cur, wflat+WOFF[7], f1, stats+7*256, nullptr, 0.f, nullptr, 0);
    CONV32(8, f1, f2, stats+7*256, iN16);
    bn_add_relu_kernel<<<32768,256,0,stream>>>(
        f2, cur, stats+8*256, 32, 16, 16, 16, 8, 2, iN16, 8388608);
    { float* t = f2; f2 = cur; cur = t; }
    // blocks 4-5: 32ch 16x16
    for (int bi = 0; bi < 2; bi++) {
        int la = 9 + bi*2, lb = 10 + bi*2;
        CONV32(la, cur, f1, nullptr, 0.f);
        CONV32(lb, f1, f2, stats+la*256, iN16);
        bn_add_relu_kernel<<<32768,256,0,stream>>>(
            f2, cur, stats+lb*256, 32, 16, 16, 32, 0, 1, iN16, 8388608);
        float* t = f2; f2 = cur; cur = t;
    }
    // block 6: stride2 32->64ch
    conv_tile<float,256, 32,64,16,16,2, 8,2,16,4, 16><<<BATCH,256,0,stream>>>(
        cur, wflat+WOFF[13], f1, stats+13*256, nullptr, 0.f, nullptr, 0);
    CONV64(14, f1, f2, stats+13*256, iN8);
    bn_add_relu_kernel<<<16384,256,0,stream>>>(
        f2, cur, stats+14*256, 64, 8, 8, 32, 16, 2, iN8, 4194304);
    { float* t = f2; f2 = cur; cur = t; }
    // blocks 7-8: 64ch 8x8
    for (int bi = 0; bi < 2; bi++) {
        int la = 15 + bi*2, lb = 16 + bi*2;
        CONV64(la, cur, f1, nullptr, 0.f);
        CONV64(lb, f1, f2, stats+la*256, iN8);
        bn_add_relu_kernel<<<16384,256,0,stream>>>(
            f2, cur, stats+lb*256, 64, 8, 8, 64, 0, 1, iN8, 4194304);
        float* t = f2; f2 = cur; cur = t;
    }

    poolfc_kernel<__hip_bfloat16><<<BATCH, 64, 0, stream>>>(
        cur, (const __hip_bfloat16*)d_in[4], (const __hip_bfloat16*)d_in[5],
        (__hip_bfloat16*)d_out, flag, 1);
    poolfc_kernel<float><<<BATCH, 64, 0, stream>>>(
        cur, (const float*)d_in[4], (const float*)d_in[5],
        (float*)d_out, flag, 0);
}